// Round 9
// baseline (382.418 us; speedup 1.0000x reference)
//
#include <hip/hip_runtime.h>

constexpr int NB    = 8;
constexpr int NN    = 256;
constexpr int F0    = 512;
constexpr int F1    = 256;
constexpr int F2    = 128;
constexpr int ROWS  = NB * NN;
constexpr int KMAX  = 30;
constexpr float INF = 1e30f;

// Skewed 256-float vector layout: chunk q (64 floats) at offset q*68 (bank-safe).
constexpr int VSTR = 272;
__device__ __forceinline__ int cmap(int j) { return (j >> 6) * 68 + (j & 63); }

// upper-triangular 4x4 tile list (10 tiles)
__device__ __constant__ int TRt[10] = {0,0,0,0,1,1,1,2,2,3};
__device__ __constant__ int TCt[10] = {0,1,2,3,1,2,3,2,3,3};

// ---------------- fp32 GEMM: C = act(A @ B + bias), 64x32 tile, BK=16 ----------
__global__ __launch_bounds__(256) void gemm_bias_act(
    const float* __restrict__ A, const float* __restrict__ B,
    const float* __restrict__ bias, float* __restrict__ C,
    int M, int Ncols, int K, int relu)
{
  __shared__ float As[16][64];
  __shared__ float Bs[16][32];
  const int tid = threadIdx.x;
  const int tx = tid & 15;
  const int ty = tid >> 4;
  const int rowBase = blockIdx.y * 64;
  const int colBase = blockIdx.x * 32;
  float acc[4][2] = {};
  for (int k0 = 0; k0 < K; k0 += 16) {
    {
      const int r  = tid >> 2;
      const int kq = (tid & 3) << 2;
      const float4 av = *(const float4*)(A + (size_t)(rowBase + r) * K + (k0 + kq));
      As[kq+0][r] = av.x; As[kq+1][r] = av.y; As[kq+2][r] = av.z; As[kq+3][r] = av.w;
      const int kr = tid >> 4;
      const int c2 = (tid & 15) << 1;
      const float2 bv = *(const float2*)(B + (size_t)(k0 + kr) * Ncols + (colBase + c2));
      Bs[kr][c2+0] = bv.x; Bs[kr][c2+1] = bv.y;
    }
    __syncthreads();
    #pragma unroll
    for (int kk = 0; kk < 16; kk++) {
      const float4 a = *(const float4*)&As[kk][ty*4];
      const float b0v = Bs[kk][tx*2+0];
      const float b1v = Bs[kk][tx*2+1];
      acc[0][0] += a.x*b0v; acc[0][1] += a.x*b1v;
      acc[1][0] += a.y*b0v; acc[1][1] += a.y*b1v;
      acc[2][0] += a.z*b0v; acc[2][1] += a.z*b1v;
      acc[3][0] += a.w*b0v; acc[3][1] += a.w*b1v;
    }
    __syncthreads();
  }
  #pragma unroll
  for (int i = 0; i < 4; i++) {
    const int rr = rowBase + ty*4 + i;
    #pragma unroll
    for (int j = 0; j < 2; j++) {
      const int cc = colBase + tx*2 + j;
      float v = acc[i][j] + bias[cc];
      if (relu) v = fmaxf(v, 0.0f);
      C[(size_t)rr * Ncols + cc] = v;
    }
  }
}

// ---------------- D[b,n,m] = 0.5*(1 - cos-sim), norms inline -------------------
__global__ __launch_bounds__(256) void corr_dist(
    const float* __restrict__ z, float* __restrict__ D)
{
  const int b = blockIdx.z;
  const float* zb = z + (size_t)b * NN * F2;
  __shared__ float As[16][64];
  __shared__ float Bs[16][64];
  const int tid = threadIdx.x;
  const int tx = tid & 15;
  const int ty = tid >> 4;
  const int rowBase = blockIdx.y * 64;
  const int colBase = blockIdx.x * 64;
  float acc[4][4] = {};
  float rn[4] = {}, cn[4] = {};
  for (int k0 = 0; k0 < F2; k0 += 16) {
    {
      const int r  = tid >> 2;
      const int kq = (tid & 3) << 2;
      const float4 av = *(const float4*)(zb + (size_t)(rowBase + r) * F2 + (k0 + kq));
      As[kq+0][r] = av.x; As[kq+1][r] = av.y; As[kq+2][r] = av.z; As[kq+3][r] = av.w;
      const float4 bv = *(const float4*)(zb + (size_t)(colBase + r) * F2 + (k0 + kq));
      Bs[kq+0][r] = bv.x; Bs[kq+1][r] = bv.y; Bs[kq+2][r] = bv.z; Bs[kq+3][r] = bv.w;
    }
    __syncthreads();
    #pragma unroll
    for (int kk = 0; kk < 16; kk++) {
      const float4 a = *(const float4*)&As[kk][ty*4];
      const float4 bq = *(const float4*)&Bs[kk][tx*4];
      const float ar[4] = {a.x, a.y, a.z, a.w};
      const float br[4] = {bq.x, bq.y, bq.z, bq.w};
      #pragma unroll
      for (int i = 0; i < 4; i++) {
        rn[i] += ar[i] * ar[i];
        cn[i] += br[i] * br[i];
        #pragma unroll
        for (int j = 0; j < 4; j++)
          acc[i][j] += ar[i] * br[j];
      }
    }
    __syncthreads();
  }
  float* Db = D + (size_t)b * NN * NN;
  #pragma unroll
  for (int i = 0; i < 4; i++) {
    const int rr = rowBase + ty*4 + i;
    #pragma unroll
    for (int j = 0; j < 4; j++) {
      const int cc = colBase + tx*4 + j;
      const float denom = sqrtf(fmaxf(rn[i] * cn[j], 1e-8f));
      Db[(size_t)rr * NN + cc] = 0.5f * (1.0f - acc[i][j] / denom);
    }
  }
}

// ---------------- fused per-batch scans + Ds matrix: 8 blocks ------------------
// Phase 1: row-wise fp64 inclusive scans (wave w handles rows [64w,64w+64))
// Phase 2: in-place 256-deep column scan, diag -> LDS
// Phase 3: A[n][j+1] = Ds[n][j] (INF below diag), C0, out init
// Intra-block global visibility guaranteed by __syncthreads (vmcnt drain).
__global__ __launch_bounds__(256) void scan_ds(
    const float* __restrict__ D, double* __restrict__ SS,
    float* __restrict__ A, float* __restrict__ Cstk, float* __restrict__ out)
{
  const int b = blockIdx.x;
  const int tid = threadIdx.x, w = tid >> 6, lane = tid & 63;
  __shared__ double diag[NN];
  const float* Db = D + (size_t)b * NN * NN;
  double* Sb = SS + (size_t)b * NN * NN;

  // Phase 1: row scans
  for (int t = 0; t < 64; t++) {
    const int n = w * 64 + t;
    const float4 dv = *(const float4*)(Db + (size_t)n * NN + lane * 4);
    double p0 = dv.x, p1 = p0 + dv.y, p2 = p1 + dv.z, p3 = p2 + dv.w;
    double tt = p3;
    #pragma unroll
    for (int d = 1; d < 64; d <<= 1) {
      double uu = __shfl_up(tt, d);
      if (lane >= d) tt += uu;
    }
    const double off = tt - p3;
    double* sr = Sb + (size_t)n * NN + lane * 4;
    sr[0] = off + p0; sr[1] = off + p1; sr[2] = off + p2; sr[3] = off + p3;
  }
  __syncthreads();

  // Phase 2: column scan (in place), capture diagonal
  {
    const int j = tid;
    double cum = 0.0;
    for (int r = 0; r < NN; r += 4) {
      double d0 = Sb[(size_t)(r+0)*NN + j];
      double d1 = Sb[(size_t)(r+1)*NN + j];
      double d2 = Sb[(size_t)(r+2)*NN + j];
      double d3 = Sb[(size_t)(r+3)*NN + j];
      cum += d0; Sb[(size_t)(r+0)*NN + j] = cum; if (r+0 == j) diag[j] = cum;
      cum += d1; Sb[(size_t)(r+1)*NN + j] = cum; if (r+1 == j) diag[j] = cum;
      cum += d2; Sb[(size_t)(r+2)*NN + j] = cum; if (r+2 == j) diag[j] = cum;
      cum += d3; Sb[(size_t)(r+3)*NN + j] = cum; if (r+3 == j) diag[j] = cum;
    }
  }
  __syncthreads();

  // Phase 3: Ds -> A (shifted by +1 col), C0 = Ds[n][N-1], out init
  float* Ab = A + (size_t)b * NN * NN;
  const int j = tid;
  const double dj = diag[j];
  for (int n = 0; n < NN; n++) {
    double snn = 0.0, sv = 0.0;
    if (n > 0) { snn = diag[n-1]; sv = Sb[(size_t)(n-1)*NN + j]; }
    const float ds = (j >= n) ? (float)(dj - 2.0 * sv + snn) : INF;
    if (j < NN - 1) Ab[(size_t)n * NN + j + 1] = ds;
    else            Cstk[(size_t)b * 32 * NN + n] = ds;
    if (j == 0)     Ab[(size_t)n * NN] = INF;
  }
  out[b * NN + j] = (j == NN - 1) ? 1.0f : 0.0f;
}

// ---------------- min-plus MM tile (upper tiles only; lower never written) -----
__device__ __forceinline__ void mm_tile(
    const float* __restrict__ P, const float* __restrict__ Q, float* __restrict__ O,
    int b, int rowBase, int colBase, float (*As)[64], float (*Bs)[64])
{
  const int tid = threadIdx.x;
  const int tx = tid & 15;
  const int ty = tid >> 4;
  const float* Pb = P + (size_t)b * NN * NN;
  const float* Qb = Q + (size_t)b * NN * NN;
  float acc[4][4];
  #pragma unroll
  for (int i = 0; i < 4; i++)
    #pragma unroll
    for (int j = 0; j < 4; j++) acc[i][j] = INF;
  const int kHi = (colBase + 64 < NN) ? colBase + 64 : NN;
  for (int k0 = rowBase; k0 < kHi; k0 += 16) {
    {
      const int r  = tid >> 2;
      const int kq = (tid & 3) << 2;
      const float4 av = *(const float4*)(Pb + (size_t)(rowBase + r) * NN + (k0 + kq));
      As[kq+0][r] = av.x; As[kq+1][r] = av.y; As[kq+2][r] = av.z; As[kq+3][r] = av.w;
      const int kr = tid >> 4;
      const int c4 = (tid & 15) << 2;
      *(float4*)&Bs[kr][c4] = *(const float4*)(Qb + (size_t)(k0 + kr) * NN + (colBase + c4));
    }
    __syncthreads();
    #pragma unroll
    for (int kk = 0; kk < 16; kk++) {
      const float4 a = *(const float4*)&As[kk][ty*4];
      const float4 bq = *(const float4*)&Bs[kk][tx*4];
      const float ar[4] = {a.x, a.y, a.z, a.w};
      const float br[4] = {bq.x, bq.y, bq.z, bq.w};
      #pragma unroll
      for (int i = 0; i < 4; i++)
        #pragma unroll
        for (int j = 0; j < 4; j++)
          acc[i][j] = fminf(acc[i][j], ar[i] + br[j]);
    }
    __syncthreads();
  }
  float* Ob = O + (size_t)b * NN * NN;
  #pragma unroll
  for (int i = 0; i < 4; i++)
    #pragma unroll
    for (int j = 0; j < 4; j++)
      Ob[(size_t)(rowBase + ty*4 + i) * NN + (colBase + tx*4 + j)] =
          fminf(acc[i][j], INF);
}

__device__ __forceinline__ void stage_blk(
    const float* __restrict__ P, float* __restrict__ Cstk,
    int b, int x, int kin, int kout, int nv, float* cs)
{
  const int vc = x >> 2, rg = x & 3;
  const int v0 = vc * 4;
  if (v0 >= nv) return;
  const int nvb = min(4, nv - v0);
  const int tid = threadIdx.x;
  float* Ck = Cstk + (size_t)b * 32 * NN;
  for (int v = 0; v < nvb; v++)
    cs[v * VSTR + cmap(tid)] = Ck[(size_t)(kin + v0 + v) * NN + tid];
  __syncthreads();
  const int n = rg * 64 + (tid >> 2);
  const int q = tid & 3;
  const float* Pr = P + (size_t)b * NN * NN + (size_t)n * NN + q * 64;
  float m[4] = {INF, INF, INF, INF};
  if (q * 64 + 63 > n) {
    #pragma unroll 4
    for (int i = 0; i < 16; i++) {
      const float4 a = *(const float4*)(Pr + i * 4);
      #pragma unroll
      for (int v = 0; v < 4; v++) {
        if (v < nvb) {
          const float4 c = *(const float4*)&cs[v * VSTR + q * 68 + i * 4];
          m[v] = fminf(m[v], fminf(fminf(a.x + c.x, a.y + c.y),
                                   fminf(a.z + c.z, a.w + c.w)));
        }
      }
    }
  }
  #pragma unroll
  for (int v = 0; v < 4; v++) {
    m[v] = fminf(m[v], __shfl_xor(m[v], 1));
    m[v] = fminf(m[v], __shfl_xor(m[v], 2));
  }
  if (q == 0) {
    for (int v = 0; v < nvb; v++)
      Ck[(size_t)(kout + v0 + v) * NN + n] = fminf(m[v], INF);
  }
}

__global__ __launch_bounds__(256) void tail(
    const float* P1, const float* Q1, float* O1, int nMM,
    const float* SP, float* Cstk, int kin, int kout, int nv)
{
  __shared__ float As[16][64];
  __shared__ float Bs[16][64];
  __shared__ __align__(16) float cs[4 * VSTR];
  const int b = blockIdx.y, zz = blockIdx.z;
  if (zz < nMM) {
    if (blockIdx.x < 10)
      mm_tile(P1, Q1, O1, b, TRt[blockIdx.x] * 64, TCt[blockIdx.x] * 64, As, Bs);
  } else {
    stage_blk(SP, Cstk, b, blockIdx.x, kin, kout, nv, cs);
  }
}

// ---------------- fused softmax: one block per (k, b), rows then cols ----------
__global__ __launch_bounds__(256) void sm_all(
    const float* __restrict__ A, const float* __restrict__ Cstk,
    float* __restrict__ out)
{
  const int k = blockIdx.x + 1;        // 1..29
  const int b = blockIdx.y;
  const int limit = NN - k;
  const int tid = threadIdx.x;
  __shared__ __align__(16) float cprev[VSTR];
  __shared__ float mrow[NN];
  __shared__ float ivh[NN];
  const float* Ckb = Cstk + (size_t)b * 32 * NN;
  cprev[cmap(tid)] = Ckb[(size_t)(k - 1) * NN + tid];
  mrow[tid]        = Ckb[(size_t)k * NN + tid];
  __syncthreads();
  const float* Ab = A + (size_t)b * NN * NN;
  const int r = tid >> 2, q = tid & 3;
  for (int rr = 0; rr < 4; rr++) {
    const int n = rr * 64 + r;
    const float m = mrow[n];
    float s = 0.f;
    if (q * 64 + 63 > n) {
      const float* Ar = Ab + (size_t)n * NN + q * 64;
      #pragma unroll 4
      for (int i = 0; i < 16; i++) {
        const float4 a = *(const float4*)(Ar + i * 4);
        const int jj = q * 64 + i * 4;
        const float4 c = *(const float4*)&cprev[q * 68 + i * 4];
        s += (jj + 0 <= limit) ? __expf(m - a.x - c.x) : 0.f;
        s += (jj + 1 <= limit) ? __expf(m - a.y - c.y) : 0.f;
        s += (jj + 2 <= limit) ? __expf(m - a.z - c.z) : 0.f;
        s += (jj + 3 <= limit) ? __expf(m - a.w - c.w) : 0.f;
      }
    }
    s += __shfl_xor(s, 1);
    s += __shfl_xor(s, 2);
    if (q == 0) ivh[n] = 1.0f / s;
  }
  __syncthreads();
  const int j = tid;
  if (j < limit) {
    const float cj = cprev[cmap(j + 1)];
    const int nmax = (j < limit - 1) ? j : limit - 1;
    float a = 0.0f;
    for (int nr = 0; nr <= nmax; nr++)
      a += __expf(mrow[nr] - Ab[(size_t)nr * NN + j + 1] - cj) * ivh[nr];
    int kmaxj = NN - 1 - j; if (kmaxj > KMAX - 1) kmaxj = KMAX - 1;
    atomicAdd(&out[b * NN + j], a / (float)((j + 1) * kmaxj));
  }
}

extern "C" void kernel_launch(void* const* d_in, const int* in_sizes, int n_in,
                              void* d_out, int out_size, void* d_ws, size_t ws_size,
                              hipStream_t stream) {
  const float* x  = (const float*)d_in[0];
  const float* W0 = (const float*)d_in[1];
  const float* b0 = (const float*)d_in[2];
  const float* W1 = (const float*)d_in[3];
  const float* b1 = (const float*)d_in[4];
  float* out = (float*)d_out;

  // ws layout — non-overlapping, ~20 MB of the 256 MiB workspace
  char* base = (char*)d_ws;
  float*  h    = (float*)(base);                          // 2 MB
  float*  z    = (float*)(base + (2u  << 20));            // 1 MB
  float*  D    = (float*)(base + (3u  << 20));            // 2 MB
  double* SS   = (double*)(base + (5u  << 20));           // 4 MB (in-place scan)
  float*  A    = (float*)(base + (9u  << 20));            // 2 MB
  float*  A2   = (float*)(base + (11u << 20));
  float*  A4   = (float*)(base + (13u << 20));
  float*  A8   = (float*)(base + (15u << 20));
  float*  A16  = (float*)(base + (17u << 20));
  float*  Cstk = (float*)(base + (19u << 20));            // 256 KB

  gemm_bias_act<<<dim3(F1/32, ROWS/64), 256, 0, stream>>>(x, W0, b0, h, ROWS, F1, F0, 1);
  gemm_bias_act<<<dim3(F2/32, ROWS/64), 256, 0, stream>>>(h, W1, b1, z, ROWS, F2, F1, 0);
  corr_dist<<<dim3(NN/64, NN/64, NB), 256, 0, stream>>>(z, D);
  scan_ds<<<dim3(NB), 256, 0, stream>>>(D, SS, A, Cstk, out);
  // T1: A2 = A(x)A; C1 = A(x)C0
  tail<<<dim3(16, NB, 2), 256, 0, stream>>>(A,  A,  A2,  1, A,   Cstk, 0, 1, 1);
  // T2: A4 = A2(x)A2; C2-3 = A2(x)C0-1
  tail<<<dim3(16, NB, 2), 256, 0, stream>>>(A2, A2, A4,  1, A2,  Cstk, 0, 2, 2);
  // T3: A8 = A4(x)A4; C4-7 = A4(x)C0-3
  tail<<<dim3(16, NB, 2), 256, 0, stream>>>(A4, A4, A8,  1, A4,  Cstk, 0, 4, 4);
  // T4: A16 = A8(x)A8; C8-15 = A8(x)C0-7
  tail<<<dim3(16, NB, 2), 256, 0, stream>>>(A8, A8, A16, 1, A8,  Cstk, 0, 8, 8);
  // T5: C16-29 = A16(x)C0-13
  tail<<<dim3(16, NB, 1), 256, 0, stream>>>(nullptr, nullptr, nullptr, 0, A16, Cstk, 0, 16, 14);
  sm_all<<<dim3(KMAX-1, NB), 256, 0, stream>>>(A, Cstk, out);
}